// Round 1
// baseline (140.182 us; speedup 1.0000x reference)
//
#include <hip/hip_runtime.h>
#include <hip/hip_bf16.h>
#include <cstdint>
#include <cstddef>

using bf16 = __hip_bfloat16;
typedef __attribute__((ext_vector_type(8))) short bf16x8v;
typedef __attribute__((ext_vector_type(4))) float f32x4v;

__device__ __forceinline__ f32x4v mfma16x16x32(bf16x8v a, bf16x8v b, f32x4v c) {
  return __builtin_amdgcn_mfma_f32_16x16x32_bf16(a, b, c, 0, 0, 0);
}

__device__ __forceinline__ void lds_async16(const void* g, void* l) {
  __builtin_amdgcn_global_load_lds(
      (__attribute__((address_space(1))) void*)g,
      (__attribute__((address_space(3))) void*)l, 16, 0, 0);
}

__device__ __forceinline__ unsigned short f2bf_bits(float f) {
  union { bf16 h; unsigned short u; } cv;
  cv.h = __float2bfloat16(f);
  return cv.u;
}

// ---------------- prep kernels ----------------

// x [4096*1024] f32 -> bf16, one float4 per thread (exact grid)
__global__ void convert_x_k(const float* __restrict__ x, bf16* __restrict__ xb) {
  const int i = blockIdx.x * blockDim.x + threadIdx.x;
  const float4 v = reinterpret_cast<const float4*>(x)[i];
  ushort4 o;
  o.x = f2bf_bits(v.x); o.y = f2bf_bits(v.y);
  o.z = f2bf_bits(v.z); o.w = f2bf_bits(v.w);
  reinterpret_cast<ushort4*>(xb)[i] = o;
}

// W[k][n] f32 -> Wt[n][k] bf16, tiled 64x64 through LDS (+1 pad).
// mats 0..2 -> wcat rows mat*1024.., mat 3 -> wot
__global__ void transpose_w_k(const float* __restrict__ Wq, const float* __restrict__ Wk,
                              const float* __restrict__ Wv, const float* __restrict__ Wo,
                              bf16* __restrict__ wcat, bf16* __restrict__ wot) {
  __shared__ float tile[64][65];
  const int mat = blockIdx.z;
  const float* W = (mat == 0) ? Wq : (mat == 1) ? Wk : (mat == 2) ? Wv : Wo;
  bf16* dst = (mat < 3) ? (wcat + (size_t)mat * 1024 * 1024) : wot;
  const int n0 = blockIdx.x * 64, k0 = blockIdx.y * 64;
  const int tr = threadIdx.x >> 6, tc = threadIdx.x & 63;
#pragma unroll
  for (int it = 0; it < 16; ++it)
    tile[it * 4 + tr][tc] = W[(size_t)(k0 + it * 4 + tr) * 1024 + n0 + tc];
  __syncthreads();
#pragma unroll
  for (int it = 0; it < 16; ++it) {
    const int n = n0 + it * 4 + tr;
    dst[(size_t)n * 1024 + k0 + tc] = __float2bfloat16(tile[tc][it * 4 + tr]);
  }
}

__global__ void build_bias_k(const float* __restrict__ bq, const float* __restrict__ bk,
                             const float* __restrict__ bv, float* __restrict__ bcat) {
  const int i = blockIdx.x * 256 + threadIdx.x;
  if (i < 3072)
    bcat[i] = (i < 1024) ? bq[i] : (i < 2048) ? bk[i - 1024] : bv[i - 2048];
}

// ---------------- GEMM: C[M,N] = A[M,K] @ Bt[N,K]^T (+bias) ----------------
// 128x128 tile, BK=32, 4 waves (2x2), each wave 64x64 = 4x4 frags of 16x16x32.
// EPI=0: N=3072, scatter to q/k [B,H,S,64] bf16 and Vt [B,H,64,S] bf16.
// EPI=1: N=1024, f32 out row-major.
template <int EPI>
__global__ __launch_bounds__(256, 2) void gemm_k(
    const bf16* __restrict__ A, const bf16* __restrict__ Bt,
    const float* __restrict__ bias,
    bf16* __restrict__ qb, bf16* __restrict__ kb, bf16* __restrict__ vtb,
    float* __restrict__ outf)
{
  constexpr int K = 1024;
  __shared__ bf16 As[128 * 32];
  __shared__ bf16 Bs[128 * 32];
  const int t = threadIdx.x;
  const int lane = t & 63, w = t >> 6;
  const int g = lane >> 4, r = lane & 15;
  const int wr = w >> 1, wc = w & 1;
  const int m0 = blockIdx.x * 128, n0 = blockIdx.y * 128;

  // staging: chunk c covers rows c*64..c*64+63; wave w rows c*64+w*16+lane/4, k8=(lane&3)*8
  const int srow = w * 16 + (lane >> 2);
  const int skoff = (lane & 3) * 8;
  const bf16* aSrc0 = A + (size_t)(m0 + srow) * K + skoff;
  const bf16* aSrc1 = aSrc0 + (size_t)64 * K;
  const bf16* bSrc0 = Bt + (size_t)(n0 + srow) * K + skoff;
  const bf16* bSrc1 = bSrc0 + (size_t)64 * K;
  bf16* aDst0 = As + w * 512;           // +lane*16B appended by HW
  bf16* aDst1 = As + 2048 + w * 512;
  bf16* bDst0 = Bs + w * 512;
  bf16* bDst1 = Bs + 2048 + w * 512;

  f32x4v acc[4][4] = {};

  for (int kt = 0; kt < K; kt += 32) {
    lds_async16(aSrc0 + kt, aDst0);
    lds_async16(aSrc1 + kt, aDst1);
    lds_async16(bSrc0 + kt, bDst0);
    lds_async16(bSrc1 + kt, bDst1);
    __syncthreads();  // drains vmcnt then barrier
    bf16x8v af[4], bfr[4];
#pragma unroll
    for (int m = 0; m < 4; ++m)
      af[m] = *reinterpret_cast<const bf16x8v*>(&As[(wr * 64 + m * 16 + r) * 32 + g * 8]);
#pragma unroll
    for (int n = 0; n < 4; ++n)
      bfr[n] = *reinterpret_cast<const bf16x8v*>(&Bs[(wc * 64 + n * 16 + r) * 32 + g * 8]);
#pragma unroll
    for (int m = 0; m < 4; ++m)
#pragma unroll
      for (int n = 0; n < 4; ++n)
        acc[m][n] = mfma16x16x32(af[m], bfr[n], acc[m][n]);
    __syncthreads();
  }

  // epilogue: C[row][col], col = lane&15, row = (lane>>4)*4 + v  [m89/m91 layout]
#pragma unroll
  for (int n = 0; n < 4; ++n) {
    const int gcol = n0 + wc * 64 + n * 16 + r;
    const float bv_ = bias[gcol];
    if (EPI == 0) {
      const int mat = gcol >> 10;      // 0=q 1=k 2=v (block-uniform)
      const int d = gcol & 1023;
      const int hh = d >> 6, dk = d & 63;
#pragma unroll
      for (int m = 0; m < 4; ++m) {
#pragma unroll
        for (int v = 0; v < 4; ++v) {
          const int grow = m0 + wr * 64 + m * 16 + g * 4 + v;
          const int b = grow >> 11, s = grow & 2047;
          const bf16 hv = __float2bfloat16(acc[m][n][v] + bv_);
          const size_t bh = (size_t)(b * 16 + hh);
          if (mat == 0)      qb[(bh * 2048 + s) * 64 + dk] = hv;
          else if (mat == 1) kb[(bh * 2048 + s) * 64 + dk] = hv;
          else               vtb[(bh * 64 + dk) * 2048 + s] = hv;  // V transposed
        }
      }
    } else {
#pragma unroll
      for (int m = 0; m < 4; ++m) {
#pragma unroll
        for (int v = 0; v < 4; ++v) {
          const int grow = m0 + wr * 64 + m * 16 + g * 4 + v;
          outf[(size_t)grow * 1024 + gcol] = acc[m][n][v] + bv_;
        }
      }
    }
  }
}

// ---------------- sliding-window flash attention ----------------
// grid (S/64, H, B), 4 waves/block; wave w owns 16 q-rows, iterates 32-key blocks.
__global__ __launch_bounds__(256, 2) void attn_k(
    const bf16* __restrict__ qb, const bf16* __restrict__ kb,
    const bf16* __restrict__ vtb, bf16* __restrict__ aout)
{
  constexpr int S = 2048;
  const int t = threadIdx.x;
  const int lane = t & 63, w = t >> 6;
  const int g = lane >> 4, r = lane & 15;
  const int h = blockIdx.y, b = blockIdx.z;
  const int q0 = blockIdx.x * 64 + w * 16;
  const size_t bh = (size_t)b * 16 + h;
  const bf16* qp = qb + bh * (S * 64);
  const bf16* kp = kb + bh * (S * 64);
  const bf16* vp = vtb + bh * (64 * S);
  __shared__ bf16 Pb[4][16][32];  // per-wave P bounce (transpose to A-layout)

  const bf16x8v qf0 = *reinterpret_cast<const bf16x8v*>(&qp[(q0 + r) * 64 + g * 8]);
  const bf16x8v qf1 = *reinterpret_cast<const bf16x8v*>(&qp[(q0 + r) * 64 + 32 + g * 8]);

  float mrun[4], lrun[4];
  f32x4v o[4] = {};
#pragma unroll
  for (int v = 0; v < 4; ++v) { mrun[v] = -1e30f; lrun[v] = 0.f; }

  int jlo = q0 - 256; if (jlo < 0) jlo = 0;
  jlo &= ~31;                          // 32-aligned, >=0; S%32==0 so no OOB
  int jhi = q0 + 15 + 256; if (jhi > S - 1) jhi = S - 1;

  const float sc = 0.125f * 1.4426950408889634f;  // 1/sqrt(64) * log2(e)

  for (int j = jlo; j <= jhi; j += 32) {
    const bf16x8v kf00 = *reinterpret_cast<const bf16x8v*>(&kp[(j + r) * 64 + g * 8]);
    const bf16x8v kf01 = *reinterpret_cast<const bf16x8v*>(&kp[(j + r) * 64 + 32 + g * 8]);
    const bf16x8v kf10 = *reinterpret_cast<const bf16x8v*>(&kp[(j + 16 + r) * 64 + g * 8]);
    const bf16x8v kf11 = *reinterpret_cast<const bf16x8v*>(&kp[(j + 16 + r) * 64 + 32 + g * 8]);

    f32x4v s0 = {}, s1 = {};
    s0 = mfma16x16x32(qf0, kf00, s0);
    s0 = mfma16x16x32(qf1, kf01, s0);
    s1 = mfma16x16x32(qf0, kf10, s1);
    s1 = mfma16x16x32(qf1, kf11, s1);

    float p0[4], p1[4], mx[4];
#pragma unroll
    for (int v = 0; v < 4; ++v) {
      const int qi = q0 + g * 4 + v;
      int d0 = qi - (j + r);      d0 = d0 < 0 ? -d0 : d0;
      int d1 = qi - (j + 16 + r); d1 = d1 < 0 ? -d1 : d1;
      p0[v] = (d0 <= 256) ? s0[v] * sc : -INFINITY;
      p1[v] = (d1 <= 256) ? s1[v] * sc : -INFINITY;
      mx[v] = fmaxf(p0[v], p1[v]);
    }
#pragma unroll
    for (int mk = 1; mk <= 8; mk <<= 1)
#pragma unroll
      for (int v = 0; v < 4; ++v)
        mx[v] = fmaxf(mx[v], __shfl_xor(mx[v], mk, 64));

    float al[4], ps[4];
#pragma unroll
    for (int v = 0; v < 4; ++v) {
      const float mnew = fmaxf(mrun[v], mx[v]);   // finite: init -1e30
      al[v] = exp2f(mrun[v] - mnew);
      p0[v] = exp2f(p0[v] - mnew);                // -inf -> 0
      p1[v] = exp2f(p1[v] - mnew);
      ps[v] = p0[v] + p1[v];
      mrun[v] = mnew;
    }
#pragma unroll
    for (int mk = 1; mk <= 8; mk <<= 1)
#pragma unroll
      for (int v = 0; v < 4; ++v)
        ps[v] += __shfl_xor(ps[v], mk, 64);

#pragma unroll
    for (int v = 0; v < 4; ++v) {
      lrun[v] = lrun[v] * al[v] + ps[v];
      Pb[w][g * 4 + v][r]      = __float2bfloat16(p0[v]);
      Pb[w][g * 4 + v][16 + r] = __float2bfloat16(p1[v]);
    }
#pragma unroll
    for (int dd = 0; dd < 4; ++dd)
#pragma unroll
      for (int v = 0; v < 4; ++v)
        o[dd][v] *= al[v];

    // wave-local LDS transpose: read P as A-frag (row=q=lane&15, k=key)
    const bf16x8v pa = *reinterpret_cast<const bf16x8v*>(&Pb[w][r][g * 8]);
#pragma unroll
    for (int dd = 0; dd < 4; ++dd) {
      const bf16x8v vf = *reinterpret_cast<const bf16x8v*>(&vp[(dd * 16 + r) * S + j + g * 8]);
      o[dd] = mfma16x16x32(pa, vf, o[dd]);
    }
  }

#pragma unroll
  for (int dd = 0; dd < 4; ++dd) {
#pragma unroll
    for (int v = 0; v < 4; ++v) {
      const int s_ = q0 + g * 4 + v;
      aout[((size_t)b * S + s_) * 1024 + h * 64 + dd * 16 + r] =
          __float2bfloat16(o[dd][v] / lrun[v]);
    }
  }
}

// ---------------- launch ----------------
extern "C" void kernel_launch(void* const* d_in, const int* in_sizes, int n_in,
                              void* d_out, int out_size, void* d_ws, size_t ws_size,
                              hipStream_t stream) {
  (void)in_sizes; (void)n_in; (void)out_size; (void)ws_size;
  const float* x  = (const float*)d_in[0];
  const float* Wq = (const float*)d_in[1];
  const float* bq = (const float*)d_in[2];
  const float* Wk = (const float*)d_in[3];
  const float* bk = (const float*)d_in[4];
  const float* Wv = (const float*)d_in[5];
  const float* bv = (const float*)d_in[6];
  const float* Wo = (const float*)d_in[7];
  const float* bo = (const float*)d_in[8];
  float* out = (float*)d_out;

  char* ws = (char*)d_ws;
  bf16*  xb    = (bf16*)(ws);                    // 8 MB  [4096][1024]
  bf16*  wcat  = (bf16*)(ws + 8388608);          // 6 MB  [3072][1024] = [Wq^T;Wk^T;Wv^T]
  bf16*  wot   = (bf16*)(ws + 14680064);         // 2 MB  [1024][1024] = Wo^T
  bf16*  qbuf  = (bf16*)(ws + 16777216);         // 8 MB  [B,H,S,64]
  bf16*  kbuf  = (bf16*)(ws + 25165824);         // 8 MB  [B,H,S,64]
  bf16*  vtbuf = (bf16*)(ws + 33554432);         // 8 MB  [B,H,64,S]
  bf16*  aoutb = (bf16*)(ws + 41943040);         // 8 MB  [B,S,1024]
  float* bcat  = (float*)(ws + 50331648);        // 12 KB [3072]

  convert_x_k<<<4096, 256, 0, stream>>>(x, xb);
  transpose_w_k<<<dim3(16, 16, 4), 256, 0, stream>>>(Wq, Wk, Wv, Wo, wcat, wot);
  build_bias_k<<<12, 256, 0, stream>>>(bq, bk, bv, bcat);

  gemm_k<0><<<dim3(32, 24), 256, 0, stream>>>(xb, wcat, bcat, qbuf, kbuf, vtbuf, nullptr);
  attn_k<<<dim3(32, 16, 2), 256, 0, stream>>>(qbuf, kbuf, vtbuf, aoutb);
  gemm_k<1><<<dim3(32, 8), 256, 0, stream>>>(aoutb, wot, bo, nullptr, nullptr, nullptr, out);
}